// Round 1
// baseline (288.059 us; speedup 1.0000x reference)
//
#include <hip/hip_runtime.h>
#include <stdint.h>
#include <math.h>

// Problem constants (fixed by the reference's setup_inputs)
#define N_BATCH 8
#define A_ELEMS 500000          // anchors per batch
#define TOPK    2000
#define NBINS   2048            // 11-bit histogram (exact-fallback path only)
#define CAP     4096            // candidate capacity per batch (expected ~3475 +- 59)
#define BCAP2   128             // per-scan-block private candidate cap (expected ~27 +- 5)
#define SBLK    128             // scan blocks per batch
#define SEG     16              // key segments for rank phase (SEG*SEGK = CAP)
#define SEGK    256             // keys per segment
#define GRP     4               // candidate groups of 1024 per batch (GRP*1024 = CAP)
#define BBOX_CLIP 4.135166556742356f  // log(1000/16)

// Monotone map float -> uint32 (ascending). Larger u <=> larger float.
__device__ __forceinline__ uint32_t f2sortable(float f) {
    uint32_t b = __float_as_uint(f);
    return (b & 0x80000000u) ? ~b : (b | 0x80000000u);
}

// ---------------- K1: scan + validate/compact + exact fallback ----------------
// Speculative threshold compact (T = 2.46: per-batch count above it is
// ~3475 +- 59 for N(0,1) scores — inside [TOPK, CAP] by >10 sigma both sides).
// Float-domain compare (monotone-equivalent to the sortable compare for the
// non-NaN inputs); sortable key built only on the rare hits.
// Last-block-per-batch closes (rocPRIM-style device-scope ticket):
//   writes -> __threadfence (release) -> __syncthreads -> atomic ticket;
//   closer: ticket==SBLK-1 -> __threadfence (acquire) -> read peers' data.
// Closer validates counts, compact-copies the 128 private lists into cand[],
// and runs the exact radix-select fallback inline if speculation failed
// (>10 sigma event — effectively never).
__global__ __launch_bounds__(256) void scan_select_kernel(
    const float* __restrict__ obj,
    uint32_t* __restrict__ tick,            // [N_BATCH], pre-zeroed
    uint32_t* __restrict__ bcount,
    unsigned long long* __restrict__ priv,
    uint32_t* __restrict__ cand_count,
    unsigned long long* __restrict__ cand)
{
    __shared__ uint32_t lcount;
    __shared__ uint32_t lticket;
    __shared__ uint32_t cs[SBLK];
    __shared__ uint32_t ps[SBLK];
    __shared__ uint32_t pre[SBLK + 1];
    __shared__ uint32_t bad;
    __shared__ uint32_t cutb;
    __shared__ uint32_t sh[NBINS];          // 8 KB, fallback path only

    const int n = blockIdx.y, blk = blockIdx.x;
    const int tid = (int)threadIdx.x;
    if (tid == 0) lcount = 0;
    __syncthreads();

    const float Tf = 2.46f;
    const float4* o4 = (const float4*)(obj + (size_t)n * A_ELEMS);
    unsigned long long* pv = priv + ((size_t)n * SBLK + blk) * BCAP2;
    const int n4 = A_ELEMS / 4;  // 125000, exact
    for (int i = blk * 256 + tid; i < n4; i += SBLK * 256) {
        float4 v = o4[i];
        float fs[4] = {v.x, v.y, v.z, v.w};
        #pragma unroll
        for (int c = 0; c < 4; ++c) {
            if (fs[c] >= Tf) {
                uint32_t pos = atomicAdd(&lcount, 1u);     // LDS atomic — rare
                if (pos < BCAP2) {
                    uint32_t idx = (uint32_t)(i * 4 + c);
                    pv[pos] = ((unsigned long long)f2sortable(fs[c]) << 32) |
                              (unsigned long long)(~idx);
                }
            }
        }
    }
    __syncthreads();                                  // lcount final, pv done
    if (tid == 0) bcount[(size_t)n * SBLK + blk] = lcount;  // uncapped
    __threadfence();                                  // release pv + bcount
    __syncthreads();                                  // all fences retired
    if (tid == 0) lticket = atomicAdd(&tick[n], 1u);
    __syncthreads();
    if (lticket != (uint32_t)(SBLK - 1)) return;      // not the closer
    __threadfence();                                  // acquire peers' writes

    // ---- validate + prefix-scan of per-block counts ----
    if (tid == 0) bad = 0;
    __syncthreads();
    if (tid < SBLK) {
        uint32_t c = bcount[(size_t)n * SBLK + tid];
        cs[tid] = c; ps[tid] = c;
        if (c > BCAP2) atomicOr(&bad, 1u);   // overflowed block -> incomplete
    }
    __syncthreads();
    for (int off = 1; off < SBLK; off <<= 1) {   // Hillis-Steele inclusive scan
        uint32_t v = 0;
        if (tid < SBLK) { v = ps[tid]; if (tid >= off) v += ps[tid - off]; }
        __syncthreads();
        if (tid < SBLK) ps[tid] = v;
        __syncthreads();
    }
    const uint32_t total = ps[SBLK - 1];
    if (tid < SBLK) pre[tid] = ps[tid] - cs[tid];
    if (tid == 0) pre[SBLK] = total;
    __syncthreads();
    const bool okl = (bad == 0) && (total >= TOPK) && (total <= CAP);
    unsigned long long* cn = cand + (size_t)n * CAP;

    if (okl) {
        if (tid == 0) cand_count[n] = total;
        // gather private lists into contiguous cand[n][0..total)
        const unsigned long long* pvb = priv + (size_t)n * SBLK * BCAP2;
        for (uint32_t g = tid; g < total; g += 256) {
            int lo = 0, hi = SBLK - 1;   // largest b with pre[b] <= g
            while (lo < hi) { int mid = (lo + hi + 1) >> 1; if (pre[mid] <= g) lo = mid; else hi = mid - 1; }
            cn[g] = pvb[(size_t)lo * BCAP2 + (g - pre[lo])];
        }
        return;
    }

    // ---- exact fallback: full radix-select over 500k scores (~never runs) ----
    for (int i = tid; i < NBINS; i += 256) sh[i] = 0;
    if (tid == 0) lcount = 0;
    __syncthreads();
    const float* o = obj + (size_t)n * A_ELEMS;
    for (int i = tid; i < A_ELEMS; i += 256)
        atomicAdd(&sh[f2sortable(o[i]) >> 21], 1u);
    __syncthreads();
    if (tid == 0) {
        uint32_t cum = 0; int b;
        for (b = NBINS - 1; b > 0; --b) { cum += sh[b]; if (cum >= TOPK) break; }
        cutb = (uint32_t)b;
    }
    __syncthreads();
    const uint32_t cb = cutb;
    for (int i = tid; i < A_ELEMS; i += 256) {
        uint32_t u = f2sortable(o[i]);
        if ((u >> 21) >= cb) {
            uint32_t pos = atomicAdd(&lcount, 1u);
            if (pos < CAP)
                cn[pos] = ((unsigned long long)u << 32) | (unsigned long long)(~(uint32_t)i);
        }
    }
    __syncthreads();
    if (tid == 0) cand_count[n] = lcount < CAP ? lcount : CAP;
}

// ---------------- K2: partial ranks + last-block decode ----------------
// rank(t) = #{j : key_j > key_t}; keys unique -> rank == final sorted position.
// Block (grp, seg, n): partial count of its 1024 candidates (4 keys/thread in
// registers) against one 256-key segment in LDS; wave-uniform ulonglong2 reads.
// Ticket per (n, grp) counts the SEG=16 segment blocks; the 16th closes and
// decodes that group's 1024 candidates (sum partials, gather, decode, write).
__global__ __launch_bounds__(256) void rank_decode_kernel(
    const float* __restrict__ anchors, const float* __restrict__ breg,
    uint32_t* __restrict__ tick,            // [N_BATCH*GRP], pre-zeroed
    const uint32_t* __restrict__ cand_count,
    const unsigned long long* __restrict__ cand,
    uint16_t* __restrict__ partial,
    float* __restrict__ out)
{
    __shared__ unsigned long long s[SEGK];   // 2 KB
    __shared__ uint32_t lticket;
    const int n = blockIdx.z, seg = blockIdx.y, grp = blockIdx.x;
    const int tid = (int)threadIdx.x;
    uint32_t cnt = cand_count[n];
    if (cnt > CAP) cnt = CAP;
    const unsigned long long* cn = cand + (size_t)n * CAP;
    // block-uniform predicate: dead candidate range / empty key segment
    const bool live = ((uint32_t)(grp * 1024) < cnt) && ((uint32_t)(seg * SEGK) < cnt);
    if (live) {
        const int ks = seg * SEGK;
        for (int i = tid; i < SEGK; i += 256)
            s[i] = ((uint32_t)(ks + i) < cnt) ? cn[ks + i] : 0ull;  // pad 0 < any key
        __syncthreads();
        const int t0 = grp * 1024 + tid;
        // keys for t >= cnt are garbage but their ranks are never consumed
        unsigned long long k0 = cn[t0], k1 = cn[t0 + 256], k2 = cn[t0 + 512], k3 = cn[t0 + 768];
        uint32_t r0 = 0, r1 = 0, r2 = 0, r3 = 0;
        const ulonglong2* s2 = (const ulonglong2*)s;
        #pragma unroll 8
        for (int j = 0; j < SEGK / 2; ++j) {
            ulonglong2 p = s2[j];                // wave-uniform broadcast read
            r0 += (p.x > k0); r0 += (p.y > k0);
            r1 += (p.x > k1); r1 += (p.y > k1);
            r2 += (p.x > k2); r2 += (p.y > k2);
            r3 += (p.x > k3); r3 += (p.y > k3);
        }
        uint16_t* pw = partial + ((size_t)n * SEG + seg) * CAP;
        pw[t0]       = (uint16_t)r0;
        pw[t0 + 256] = (uint16_t)r1;
        pw[t0 + 512] = (uint16_t)r2;
        pw[t0 + 768] = (uint16_t)r3;
    }
    // ticket: EVERY block of (n,grp) ticks, live or not
    __threadfence();                                  // release partials
    __syncthreads();                                  // all fences retired
    if (tid == 0) lticket = atomicAdd(&tick[(size_t)n * GRP + grp], 1u);
    __syncthreads();
    if (lticket != (uint32_t)(SEG - 1)) return;       // not the closer
    __threadfence();                                  // acquire peers' partials

    // ---- decode this (n,grp)'s candidates t in [grp*1024, grp*1024+1024) ----
    const int nseg = (int)((cnt + SEGK - 1) / SEGK);  // only written segments
    const uint16_t* pp = partial + (size_t)n * SEG * CAP;
    for (int t = grp * 1024 + tid; t < grp * 1024 + 1024; t += 256) {
        if ((uint32_t)t >= cnt) break;
        uint32_t rank = 0;
        for (int sg = 0; sg < nseg; ++sg) rank += pp[(size_t)sg * CAP + t];
        if (rank >= TOPK) continue;
        const unsigned long long mykey = cn[t];
        const uint32_t u    = (uint32_t)(mykey >> 32);
        const uint32_t idx  = ~((uint32_t)mykey);
        const uint32_t bits = (u & 0x80000000u) ? (u ^ 0x80000000u) : ~u;
        const float score = __uint_as_float(bits);
        const float4 a = ((const float4*)anchors)[(size_t)n * A_ELEMS + idx];
        const float4 b = ((const float4*)breg)[(size_t)n * A_ELEMS + idx];
        float w  = a.z - a.x + 1.0f;
        float h  = a.w - a.y + 1.0f;
        float cx = a.x + 0.5f * w;
        float cy = a.y + 0.5f * h;
        float dw = fminf(b.z, BBOX_CLIP);
        float dh = fminf(b.w, BBOX_CLIP);
        float pcx = b.x * w + cx;
        float pcy = b.y * h + cy;
        float pw  = expf(dw) * w;
        float ph  = expf(dh) * h;
        float* row = out + ((size_t)n * TOPK + rank) * 5;
        row[0] = pcx - 0.5f * pw;
        row[1] = pcy - 0.5f * ph;
        row[2] = pcx + 0.5f * pw - 1.0f;
        row[3] = pcy + 0.5f * ph - 1.0f;
        row[4] = score;
    }
}

extern "C" void kernel_launch(void* const* d_in, const int* in_sizes, int n_in,
                              void* d_out, int out_size, void* d_ws, size_t ws_size,
                              hipStream_t stream) {
    const float* anchors    = (const float*)d_in[0];  // [8,500000,4]
    const float* objectness = (const float*)d_in[1];  // [8,500000,1]
    const float* breg       = (const float*)d_in[2];  // [8,500000,4]
    float* out = (float*)d_out;                        // [8,2000,5]

    // Workspace layout (every region written-before-read each call; tickets
    // zeroed by the memset below):
    //   [0,       32)       tick1       uint32[8]        (K1 per-batch ticket)
    //   [32,      160)      tick2       uint32[8][4]     (K2 per-(n,grp) ticket)
    //   [256,     4352)     bcount      uint32[8][128]
    //   [8192,    1056768)  priv        uint64[8][128][128]
    //   [1056768, 1056800)  cand_count  uint32[8]
    //   [1056800, 1318944)  cand        uint64[8][4096]
    //   [1318944, 2367520)  partial     uint16[8][16][4096]
    uint8_t* ws = (uint8_t*)d_ws;
    uint32_t* tick1      = (uint32_t*)ws;
    uint32_t* tick2      = (uint32_t*)(ws + 32);
    uint32_t* bcount     = (uint32_t*)(ws + 256);
    unsigned long long* priv = (unsigned long long*)(ws + 8192);
    uint32_t* cand_count = (uint32_t*)(ws + 1056768);
    unsigned long long* cand = (unsigned long long*)(ws + 1056800);
    uint16_t* partial    = (uint16_t*)(ws + 1318944);

    hipMemsetAsync(ws, 0, 256, stream);   // zero both ticket arrays (capturable)
    dim3 g1(SBLK, N_BATCH);
    scan_select_kernel<<<g1, 256, 0, stream>>>(objectness, tick1, bcount, priv,
                                               cand_count, cand);
    dim3 g2(GRP, SEG, N_BATCH);
    rank_decode_kernel<<<g2, 256, 0, stream>>>(anchors, breg, tick2, cand_count,
                                               cand, partial, out);
}

// Round 2
// 149.839 us; speedup vs baseline: 1.9225x; 1.9225x over previous
//
#include <hip/hip_runtime.h>
#include <stdint.h>
#include <math.h>

// Problem constants (fixed by the reference's setup_inputs)
#define N_BATCH 8
#define A_ELEMS 500000          // anchors per batch
#define TOPK    2000
#define NBINS   2048            // 11-bit histogram (exact-fallback path only)
#define CAP     4096            // candidate capacity per batch (expected ~3475 +- 59)
#define BCAP2   128             // per-scan-block private candidate cap (expected ~27 +- 5)
#define SBLK    128             // scan blocks per batch
#define SEG     16              // key segments for rank phase (SEG*SEGK = CAP)
#define SEGK    256             // keys per segment
#define GRP     4               // candidate groups of 1024 per batch (GRP*1024 = CAP)
#define FBCAP   8192            // fallback candidate capacity (fits in priv region)
#define BBOX_CLIP 4.135166556742356f  // log(1000/16)

// Lesson from round 1 (measured): fusing across grid-wide dependencies with
// device-scope __threadfence() tickets cost ~90 us in L2 writeback/invalidate
// storms (1024 blocks x agent fence on non-coherent XCD L2s). Kernel-launch
// boundaries provide the same coherence for ~2-4 us each. This version keeps
// the fence-free round-0 structure but eliminates the check/repair kernels:
// the compaction map (prefix sums of 128 per-block counts) is recomputed
// per-block in rank/decode (cheap, parallel), and the exact fallback lives in
// decode block 0 (never taken for the fixed input seed).

// Monotone map float -> uint32 (ascending). Larger u <=> larger float.
__device__ __forceinline__ uint32_t f2sortable(float f) {
    uint32_t b = __float_as_uint(f);
    return (b & 0x80000000u) ? ~b : (b | 0x80000000u);
}

// Gather the g-th candidate (in block-major compacted order) from the private
// per-scan-block lists, given the exclusive prefix table pre[0..SBLK].
__device__ __forceinline__ unsigned long long gather_key(
    const unsigned long long* pvb, const uint32_t* pre, uint32_t g) {
    int lo = 0, hi = SBLK - 1;   // largest b with pre[b] <= g
    while (lo < hi) { int mid = (lo + hi + 1) >> 1; if (pre[mid] <= g) lo = mid; else hi = mid - 1; }
    return pvb[(size_t)lo * BCAP2 + (g - pre[lo])];
}

// ---------------- pass 1: speculative threshold compact (hot path) ----------------
// Static threshold T = 2.46: for N(0,1) scores the per-batch count above it is
// ~3475 +- 59 — inside [TOPK, CAP] by >10 sigma on both sides. Pure streaming
// read; candidates staged via one LDS counter into a PRIVATE per-block list
// (no global atomics, no fences, no pre-zero). key = (sortable<<32)|~idx:
// key desc == score desc, index asc (exact jax.lax.top_k order; keys unique).
__global__ __launch_bounds__(256) void scan_kernel(const float* __restrict__ obj,
                                                   uint32_t* __restrict__ bcount,
                                                   unsigned long long* __restrict__ priv) {
    __shared__ uint32_t lcount;
    const int n = blockIdx.y, blk = blockIdx.x;
    const int tid = (int)threadIdx.x;
    if (tid == 0) lcount = 0;
    __syncthreads();
    const float Tf = 2.46f;                    // float-domain compare (no NaNs in input)
    const float4* o4 = (const float4*)(obj + (size_t)n * A_ELEMS);
    unsigned long long* pv = priv + ((size_t)n * SBLK + blk) * BCAP2;
    const int n4 = A_ELEMS / 4;  // 125000, exact
    for (int i = blk * 256 + tid; i < n4; i += SBLK * 256) {
        float4 v = o4[i];
        float fs[4] = {v.x, v.y, v.z, v.w};
        #pragma unroll
        for (int c = 0; c < 4; ++c) {
            if (fs[c] >= Tf) {
                uint32_t pos = atomicAdd(&lcount, 1u);     // LDS atomic — rare (~0.07%)
                if (pos < BCAP2) {
                    uint32_t idx = (uint32_t)(i * 4 + c);
                    pv[pos] = ((unsigned long long)f2sortable(fs[c]) << 32) |
                              (unsigned long long)(~idx);
                }
            }
        }
    }
    __syncthreads();
    if (tid == 0) bcount[(size_t)n * SBLK + blk] = lcount;   // uncapped (overflow check)
}

// Shared per-block prologue for rank/decode: load the 128 per-block counts,
// prefix-scan them in LDS, detect overflow. Returns total; pre[] filled.
// Cost: ~128 global loads (512 B, L2/L3-hit) + 7 Hillis-Steele steps.
__device__ __forceinline__ uint32_t build_prefix(
    const uint32_t* bcount, int n, int tid,
    uint32_t* cs, uint32_t* ps, uint32_t* pre, uint32_t* bad) {
    if (tid == 0) *bad = 0;
    __syncthreads();
    if (tid < SBLK) {
        uint32_t c = bcount[(size_t)n * SBLK + tid];
        cs[tid] = c; ps[tid] = c;
        if (c > BCAP2) atomicOr(bad, 1u);   // overflowed block -> list incomplete
    }
    __syncthreads();
    for (int off = 1; off < SBLK; off <<= 1) {   // Hillis-Steele inclusive scan
        uint32_t v = 0;
        if (tid < SBLK) { v = ps[tid]; if (tid >= off) v += ps[tid - off]; }
        __syncthreads();
        if (tid < SBLK) ps[tid] = v;
        __syncthreads();
    }
    const uint32_t total = ps[SBLK - 1];
    if (tid < SBLK) pre[tid] = ps[tid] - cs[tid];
    if (tid == 0) pre[SBLK] = total;
    __syncthreads();
    return total;
}

// ---------------- pass 2: partial ranks ----------------
// rank(t) = #{j : key_j > key_t}; keys unique -> rank == final sorted position.
// Block (grp, seg, n): partial count of its 1024 candidates (4 keys/thread in
// registers, gathered on-the-fly from priv) against one 256-key segment in LDS.
__global__ __launch_bounds__(256) void rank_partial_kernel(
    const uint32_t* __restrict__ bcount,
    const unsigned long long* __restrict__ priv,
    uint16_t* __restrict__ partial) {
    __shared__ unsigned long long s[SEGK];   // 2 KB
    __shared__ uint32_t cs[SBLK], ps[SBLK], pre[SBLK + 1], bad;
    const int n = blockIdx.z, seg = blockIdx.y, grp = blockIdx.x;
    const int tid = (int)threadIdx.x;
    const uint32_t total = build_prefix(bcount, n, tid, cs, ps, pre, &bad);
    const bool okl = (bad == 0) && (total >= TOPK) && (total <= CAP);
    if (!okl) return;                           // decode block 0 runs exact fallback
    const uint32_t cnt = total;
    if ((uint32_t)(grp * 1024) >= cnt) return;  // dead candidate range
    if ((uint32_t)(seg * SEGK) >= cnt) return;  // empty key segment
    const unsigned long long* pvb = priv + (size_t)n * SBLK * BCAP2;
    const int ks = seg * SEGK;
    for (int i = tid; i < SEGK; i += 256)
        s[i] = ((uint32_t)(ks + i) < cnt) ? gather_key(pvb, pre, ks + i) : 0ull; // pad 0 < any key
    const uint32_t t0 = (uint32_t)(grp * 1024 + tid);
    // clamp gathers for t >= cnt: those ranks are never consumed
    const uint32_t cm = cnt - 1;
    unsigned long long k0 = gather_key(pvb, pre, t0 < cm ? t0 : cm);
    unsigned long long k1 = gather_key(pvb, pre, t0 + 256 < cm ? t0 + 256 : cm);
    unsigned long long k2 = gather_key(pvb, pre, t0 + 512 < cm ? t0 + 512 : cm);
    unsigned long long k3 = gather_key(pvb, pre, t0 + 768 < cm ? t0 + 768 : cm);
    __syncthreads();
    uint32_t r0 = 0, r1 = 0, r2 = 0, r3 = 0;
    const ulonglong2* s2 = (const ulonglong2*)s;
    #pragma unroll 8
    for (int j = 0; j < SEGK / 2; ++j) {
        ulonglong2 p = s2[j];                // wave-uniform broadcast read
        r0 += (p.x > k0); r0 += (p.y > k0);
        r1 += (p.x > k1); r1 += (p.y > k1);
        r2 += (p.x > k2); r2 += (p.y > k2);
        r3 += (p.x > k3); r3 += (p.y > k3);
    }
    uint16_t* pw = partial + ((size_t)n * SEG + seg) * CAP;
    pw[t0]       = (uint16_t)r0;
    pw[t0 + 256] = (uint16_t)r1;
    pw[t0 + 512] = (uint16_t)r2;
    pw[t0 + 768] = (uint16_t)r3;
}

// ---------------- pass 3: sum partials, gather, decode, write ----------------
// Also hosts the exact fallback (block grp==0) — never taken for the fixed
// input seed (speculation holds by >10 sigma; verified absmax=0).
__global__ __launch_bounds__(256) void decode_kernel(
    const float* __restrict__ anchors, const float* __restrict__ breg,
    const float* __restrict__ obj,
    const uint32_t* __restrict__ bcount,
    unsigned long long* __restrict__ priv,      // non-const: fallback reuses it
    const uint16_t* __restrict__ partial,
    float* __restrict__ out) {
    __shared__ uint32_t cs[SBLK], ps[SBLK], pre[SBLK + 1], bad;
    __shared__ uint32_t sh[NBINS];              // 8 KB, fallback only
    __shared__ uint32_t lcnt, cutb;
    const int n = blockIdx.y;
    const int tid = (int)threadIdx.x;
    const uint32_t total = build_prefix(bcount, n, tid, cs, ps, pre, &bad);
    const bool okl = (bad == 0) && (total >= TOPK) && (total <= CAP);

    if (okl) {
        const uint32_t cnt = total;
        const uint32_t t = (uint32_t)(blockIdx.x * 256 + tid);
        if (t >= cnt) return;
        const int nseg = (int)((cnt + SEGK - 1) / SEGK);   // only written segments
        const uint16_t* pp = partial + (size_t)n * SEG * CAP;
        uint32_t rank = 0;
        for (int sg = 0; sg < nseg; ++sg) rank += pp[(size_t)sg * CAP + t];
        if (rank >= TOPK) return;
        const unsigned long long* pvb = priv + (size_t)n * SBLK * BCAP2;
        const unsigned long long mykey = gather_key(pvb, pre, t);
        const uint32_t u    = (uint32_t)(mykey >> 32);
        const uint32_t idx  = ~((uint32_t)mykey);
        const uint32_t bits = (u & 0x80000000u) ? (u ^ 0x80000000u) : ~u;
        const float score = __uint_as_float(bits);
        const float4 a = ((const float4*)anchors)[(size_t)n * A_ELEMS + idx];
        const float4 b = ((const float4*)breg)[(size_t)n * A_ELEMS + idx];
        float w  = a.z - a.x + 1.0f;
        float h  = a.w - a.y + 1.0f;
        float cx = a.x + 0.5f * w;
        float cy = a.y + 0.5f * h;
        float dw = fminf(b.z, BBOX_CLIP);
        float dh = fminf(b.w, BBOX_CLIP);
        float pcx = b.x * w + cx;
        float pcy = b.y * h + cy;
        float pw  = expf(dw) * w;
        float ph  = expf(dh) * h;
        float* row = out + ((size_t)n * TOPK + rank) * 5;
        row[0] = pcx - 0.5f * pw;
        row[1] = pcy - 0.5f * ph;
        row[2] = pcx + 0.5f * pw - 1.0f;
        row[3] = pcy + 0.5f * ph - 1.0f;
        row[4] = score;
        return;
    }

    // ---- exact fallback: single block per bad batch (~never runs) ----
    if (blockIdx.x != 0) return;
    for (int i = tid; i < NBINS; i += 256) sh[i] = 0;
    if (tid == 0) lcnt = 0;
    __syncthreads();
    const float* o = obj + (size_t)n * A_ELEMS;
    for (int i = tid; i < A_ELEMS; i += 256)
        atomicAdd(&sh[f2sortable(o[i]) >> 21], 1u);
    __syncthreads();
    if (tid == 0) {
        uint32_t cum = 0; int b;
        for (b = NBINS - 1; b > 0; --b) { cum += sh[b]; if (cum >= TOPK) break; }
        cutb = (uint32_t)b;
    }
    __syncthreads();
    const uint32_t cb = cutb;
    unsigned long long* fbn = priv + (size_t)n * SBLK * BCAP2;  // 16384 slots, safe to reuse
    for (int i = tid; i < A_ELEMS; i += 256) {
        uint32_t u = f2sortable(o[i]);
        if ((u >> 21) >= cb) {
            uint32_t pos = atomicAdd(&lcnt, 1u);
            if (pos < FBCAP)
                fbn[pos] = ((unsigned long long)u << 32) | (unsigned long long)(~(uint32_t)i);
        }
    }
    __syncthreads();
    const uint32_t cnt2 = lcnt < FBCAP ? lcnt : FBCAP;
    // brute-force rank + decode (slow but correct; never executed)
    for (uint32_t t = tid; t < cnt2; t += 256) {
        const unsigned long long myk = fbn[t];
        uint32_t rank = 0;
        for (uint32_t j = 0; j < cnt2; ++j) rank += (fbn[j] > myk);
        if (rank >= TOPK) continue;
        const uint32_t u    = (uint32_t)(myk >> 32);
        const uint32_t idx  = ~((uint32_t)myk);
        const uint32_t bits = (u & 0x80000000u) ? (u ^ 0x80000000u) : ~u;
        const float score = __uint_as_float(bits);
        const float4 a = ((const float4*)anchors)[(size_t)n * A_ELEMS + idx];
        const float4 b = ((const float4*)breg)[(size_t)n * A_ELEMS + idx];
        float w  = a.z - a.x + 1.0f;
        float h  = a.w - a.y + 1.0f;
        float cx = a.x + 0.5f * w;
        float cy = a.y + 0.5f * h;
        float dw = fminf(b.z, BBOX_CLIP);
        float dh = fminf(b.w, BBOX_CLIP);
        float pcx = b.x * w + cx;
        float pcy = b.y * h + cy;
        float pw  = expf(dw) * w;
        float ph  = expf(dh) * h;
        float* row = out + ((size_t)n * TOPK + rank) * 5;
        row[0] = pcx - 0.5f * pw;
        row[1] = pcy - 0.5f * ph;
        row[2] = pcx + 0.5f * pw - 1.0f;
        row[3] = pcy + 0.5f * ph - 1.0f;
        row[4] = score;
    }
}

extern "C" void kernel_launch(void* const* d_in, const int* in_sizes, int n_in,
                              void* d_out, int out_size, void* d_ws, size_t ws_size,
                              hipStream_t stream) {
    const float* anchors    = (const float*)d_in[0];  // [8,500000,4]
    const float* objectness = (const float*)d_in[1];  // [8,500000,1]
    const float* breg       = (const float*)d_in[2];  // [8,500000,4]
    float* out = (float*)d_out;                        // [8,2000,5]

    // Workspace layout (every region written-before-read each call):
    //   [0,       4096)     bcount   uint32[8][128]
    //   [4096,    1052672)  priv     uint64[8][128][128]   (also fallback area)
    //   [1052672, 2101248)  partial  uint16[8][16][4096]
    uint8_t* ws = (uint8_t*)d_ws;
    uint32_t* bcount         = (uint32_t*)ws;
    unsigned long long* priv = (unsigned long long*)(ws + 4096);
    uint16_t* partial        = (uint16_t*)(ws + 1052672);

    dim3 g1(SBLK, N_BATCH);
    scan_kernel<<<g1, 256, 0, stream>>>(objectness, bcount, priv);
    dim3 g2(GRP, SEG, N_BATCH);
    rank_partial_kernel<<<g2, 256, 0, stream>>>(bcount, priv, partial);
    dim3 g3(CAP / 256, N_BATCH);
    decode_kernel<<<g3, 256, 0, stream>>>(anchors, breg, objectness, bcount, priv,
                                          partial, out);
}